// Round 6
// baseline (598.092 us; speedup 1.0000x reference)
//
#include <hip/hip_runtime.h>

typedef unsigned short u16;
typedef unsigned int u32;
typedef __bf16 bf16x8 __attribute__((ext_vector_type(8)));
typedef float f32x4 __attribute__((ext_vector_type(4)));
typedef u16 u16x8 __attribute__((ext_vector_type(8)));

__device__ __forceinline__ u16 f2bf(float f) {
    __bf16 h = (__bf16)f;
    return __builtin_bit_cast(u16, h);
}
__device__ __forceinline__ float bf2f(u16 u) {
    unsigned int x = ((unsigned int)u) << 16;
    return __builtin_bit_cast(float, x);
}

union FragU { u16x8 u; bf16x8 v; };

// unaligned (4B-aligned) float4 load
struct __attribute__((packed)) F4P { f32x4 v; };
__device__ __forceinline__ f32x4 ld4u(const float* p) { return ((const F4P*)p)->v; }

// ---------------- workspace layout (float offsets) ----------------
// 16-float guards around vector-loaded buffers (conv64 reads base-1 .. end+2).
constexpr size_t FEAT_A = 16;       // 917504 = max(4*64*2016, 14*64*1024)
constexpr size_t FEAT_B = 917536;   // 917504
constexpr size_t FEATBF = 1835056;  // 258048 floats = 516096 u16, layout [bs][2016][64]
constexpr size_t NOVEL  = 2093120;  // 14336  [b*7+v][1024]
constexpr size_t BARS   = 2107472;  // 16 u32 barrier counters (zeroed by init_kernel)

// ---------------- shared-memory union across stages ----------------
struct __align__(16) MlpShared {
    u16 w1[67 * 64];            // 8576 B
    u16 w2[64 * 64];            // 8192 B
    float vec[7 * 64];          // b1,b2,w3,cw,w1r0,w1r65,w1r66
    float flow[256];
    float epi[256];
    u16 base[256 * 72];         // SBS=72 row stride
    float nv[2][7][4];
    float cf[2][7][4];
};
union SharedU {
    MlpShared mlp;
    float red[256];             // convlast reduction
};

// ---------------- barrier init (runs every launch; stream-ordered) --------
__global__ void init_kernel(u32* bar) {
    if (threadIdx.x < 16) bar[threadIdx.x] = 0u;
}

// ---------------- device-scope grid barrier (256 blocks co-resident) ------
// __syncthreads drains this block's stores (compiler emits vmcnt(0) before
// s_barrier); t0's __threadfence (agent) writes back L2; acquire spin-load
// invalidates caches before the post-barrier reads.
__device__ __forceinline__ void gbar(u32* bar, int i) {
    __syncthreads();
    if (threadIdx.x == 0) {
        __threadfence();
        atomicAdd(bar + i, 1u);
        while (__hip_atomic_load(bar + i, __ATOMIC_ACQUIRE, __HIP_MEMORY_SCOPE_AGENT) < 256u)
            __builtin_amdgcn_s_sleep(2);
        __threadfence();
    }
    __syncthreads();
}

// ---------------- 3-channel 3x3 SAME conv unit ----------------------------
template<int OG>
__device__ __forceinline__ void conv3_unit(
    const float* __restrict__ in0, const float* __restrict__ in1,
    const float* __restrict__ in2,
    const float* __restrict__ wts, const float* __restrict__ bias,
    float* __restrict__ outf, int H, int W, int c0, int p, int m, int Cout)
{
    const int HW = H * W;
    if (p >= HW) return;
    const int y = p / W, x = p - y * W;

    float acc[OG];
#pragma unroll
    for (int og = 0; og < OG; ++og) acc[og] = bias[c0 + og];

#pragma unroll
    for (int cin = 0; cin < 3; ++cin) {
        const float* ip = (cin == 0 ? in0 : (cin == 1 ? in1 : in2)) + (size_t)m * HW;
        float tap[9];
#pragma unroll
        for (int dy = 0; dy < 3; ++dy) {
            int yy = y + dy - 1;
            bool ry = (yy >= 0) && (yy < H);
#pragma unroll
            for (int dx = 0; dx < 3; ++dx) {
                int xx = x + dx - 1;
                bool ok = ry && (xx >= 0) && (xx < W);
                tap[dy * 3 + dx] = ok ? ip[yy * W + xx] : 0.f;
            }
        }
#pragma unroll
        for (int og = 0; og < OG; ++og) {
            const float* wr = wts + ((size_t)(c0 + og) * 3 + cin) * 9;
#pragma unroll
            for (int j = 0; j < 9; ++j) acc[og] = fmaf(tap[j], wr[j], acc[og]);
        }
    }
#pragma unroll
    for (int og = 0; og < OG; ++og)
        outf[((size_t)m * Cout + c0 + og) * HW + p] = fmaxf(acc[og], 0.f);
}

// ---------------- 64-channel 3x3 SAME conv unit, vectorized rows ----------
// 2 px x 2 och per thread; 3 unaligned dwordx4 row loads per cin + 36 FMA.
template<int OUTMODE>  // 0: f32 NCHW (+relu); 1: bf16 [m][p][64] (+relu)
__device__ __forceinline__ void conv64_unit(
    const float* __restrict__ in, const float* __restrict__ wts,
    const float* __restrict__ bias,
    float* __restrict__ outf, u16* __restrict__ outb,
    int H, int W, int W2, int Cout, int c0, int p2, int m)
{
    const int HW = H * W;
    const int y = p2 / W2;
    const int x0 = (p2 - y * W2) * 2;
    const bool xlo = (x0 == 0);
    const bool ze2 = (x0 + 1 > W - 1);
    const bool ze3 = (x0 + 2 > W - 1);
    const bool px1ok = (x0 + 1 < W);
    const bool y0ok = (y > 0);
    const bool y2ok = (y + 1 < H);

    float a00 = bias[c0],     a01 = a00;
    float a10 = bias[c0 + 1], a11 = a10;

    const float* ipm = in + (size_t)m * 64 * HW + y * W + (x0 - 1);
    const float* wb0 = wts + (size_t)c0 * 64 * 9;
    const float* wb1 = wts + (size_t)(c0 + 1) * 64 * 9;
    const f32x4 zz = {0.f, 0.f, 0.f, 0.f};

#pragma unroll 2
    for (int cin = 0; cin < 64; ++cin) {
        const float* ip = ipm + (size_t)cin * HW;
        f32x4 r0 = y0ok ? ld4u(ip - W) : zz;
        f32x4 r1 = ld4u(ip);
        f32x4 r2 = y2ok ? ld4u(ip + W) : zz;
        if (xlo) { r0[0] = 0.f; r1[0] = 0.f; r2[0] = 0.f; }
        if (ze2) { r0[2] = 0.f; r1[2] = 0.f; r2[2] = 0.f; }
        if (ze3) { r0[3] = 0.f; r1[3] = 0.f; r2[3] = 0.f; }
        const float* w0 = wb0 + cin * 9;
        const float* w1 = wb1 + cin * 9;
#pragma unroll
        for (int dy = 0; dy < 3; ++dy) {
            f32x4 r = (dy == 0) ? r0 : ((dy == 1) ? r1 : r2);
            float wa0 = w0[dy * 3], wa1 = w0[dy * 3 + 1], wa2 = w0[dy * 3 + 2];
            float wc0 = w1[dy * 3], wc1 = w1[dy * 3 + 1], wc2 = w1[dy * 3 + 2];
            a00 = fmaf(r[0], wa0, a00); a00 = fmaf(r[1], wa1, a00); a00 = fmaf(r[2], wa2, a00);
            a01 = fmaf(r[1], wa0, a01); a01 = fmaf(r[2], wa1, a01); a01 = fmaf(r[3], wa2, a01);
            a10 = fmaf(r[0], wc0, a10); a10 = fmaf(r[1], wc1, a10); a10 = fmaf(r[2], wc2, a10);
            a11 = fmaf(r[1], wc0, a11); a11 = fmaf(r[2], wc1, a11); a11 = fmaf(r[3], wc2, a11);
        }
    }

    a00 = fmaxf(a00, 0.f); a01 = fmaxf(a01, 0.f);
    a10 = fmaxf(a10, 0.f); a11 = fmaxf(a11, 0.f);
    const int p0 = y * W + x0;
    if constexpr (OUTMODE == 0) {
        outf[((size_t)m * Cout + c0) * HW + p0] = a00;
        outf[((size_t)m * Cout + c0 + 1) * HW + p0] = a10;
        if (px1ok) {
            outf[((size_t)m * Cout + c0) * HW + p0 + 1] = a01;
            outf[((size_t)m * Cout + c0 + 1) * HW + p0 + 1] = a11;
        }
    } else {
        u32 v0 = (u32)f2bf(a00) | ((u32)f2bf(a10) << 16);
        *(u32*)(outb + ((size_t)m * HW + p0) * 64 + c0) = v0;
        if (px1ok) {
            u32 v1 = (u32)f2bf(a01) | ((u32)f2bf(a11) << 16);
            *(u32*)(outb + ((size_t)m * HW + p0 + 1) * 64 + c0) = v1;
        }
    }
}

// ---------------- final 64->1 conv + bias + residual unit -----------------
__device__ __forceinline__ void convlast_unit(
    const float* __restrict__ in, const float* __restrict__ wts,
    const float* __restrict__ bias, const float* __restrict__ resid,
    float* __restrict__ out, int x16, int m, float* red, int t)
{
    const int pxl = t & 63;
    const int sp = t >> 6;
    const int px = x16 * 64 + pxl;
    const int y = px >> 5, x = px & 31;
    float a = 0.f;
    const float* im = in + ((size_t)m * 64 + sp * 16) * 1024 + y * 32 + x;
#pragma unroll 2
    for (int ci = 0; ci < 16; ++ci) {
        const float* ip = im + ci * 1024;
        const float* wr = wts + (sp * 16 + ci) * 9;
#pragma unroll
        for (int dy = 0; dy < 3; ++dy) {
            int yy = y + dy - 1;
            if (yy < 0 || yy >= 32) continue;
#pragma unroll
            for (int dx = 0; dx < 3; ++dx) {
                int xx = x + dx - 1;
                if (xx < 0 || xx >= 32) continue;
                a = fmaf(ip[(dy - 1) * 32 + (dx - 1)], wr[dy * 3 + dx], a);
            }
        }
    }
    red[t] = a;
    __syncthreads();
    if (t < 64) {
        int p = x16 * 64 + t;
        out[(size_t)m * 1024 + p] = red[t] + red[t + 64] + red[t + 128] + red[t + 192]
                                  + bias[0] + resid[(size_t)m * 1024 + p];
    }
}

// ---------------- MLP stage (MFMA) — round-5 logic, 2 n-group iters -------
__device__ __forceinline__ void mlp_stage(
    MlpShared& S,
    const float* __restrict__ lf, const float* __restrict__ flow,
    const u16* __restrict__ feat,
    const float* __restrict__ w1, const float* __restrict__ b1,
    const float* __restrict__ w2, const float* __restrict__ b2,
    const float* __restrict__ w3, const float* __restrict__ b3g,
    const float* __restrict__ cw, const float* __restrict__ cbg,
    float* __restrict__ novel, int blk, int t)
{
    constexpr int SBS = 72;
    const int b = blk >> 7;
    const int n0base = (blk & 127) * 8;
    const int w = t >> 6, lane = t & 63, q = lane >> 4, l15 = lane & 15;
    const int sw = w >> 1;
    const int bsw = b * 2 + sw;

    for (int i = t; i < 67 * 64; i += 256) S.w1[i] = f2bf(w1[i]);
    for (int i = t; i < 64 * 64; i += 256) S.w2[i] = f2bf(w2[i]);
    if (t < 64) {
        S.vec[t]       = b1[t];
        S.vec[64 + t]  = b2[t];
        S.vec[128 + t] = w3[t];
        S.vec[192 + t] = cw[t];
        S.vec[256 + t] = w1[t];            // row 0: flow weight
        S.vec[320 + t] = w1[65 * 64 + t];  // row 65: spatial
        S.vec[384 + t] = w1[66 * 64 + t];  // row 66: ang
    }
    __syncthreads();

    const float b3s = b3g[0];
    const float cbs = cbg[0];

    // iter-invariant register preloads
    FragU w1b[2][4];
#pragma unroll
    for (int ks = 0; ks < 2; ++ks)
#pragma unroll
        for (int nt = 0; nt < 4; ++nt)
#pragma unroll
            for (int jj = 0; jj < 8; ++jj)
                w1b[ks][nt].u[jj] = S.w1[(1 + ks * 32 + q * 8 + jj) * 64 + nt * 16 + l15];

    FragU w2a[4][2]; // A = W2^T
#pragma unroll
    for (int mt = 0; mt < 4; ++mt)
#pragma unroll
        for (int ks = 0; ks < 2; ++ks)
#pragma unroll
            for (int jj = 0; jj < 8; ++jj)
                w2a[mt][ks].u[jj] = S.w2[(ks * 32 + q * 8 + jj) * 64 + mt * 16 + l15];

    float w1r0pl[4], w1r65pl[4], b1pl[4];
#pragma unroll
    for (int nt = 0; nt < 4; ++nt) {
        int j1 = nt * 16 + l15;
        w1r0pl[nt]  = S.vec[256 + j1];
        w1r65pl[nt] = S.vec[320 + j1];
        b1pl[nt]    = S.vec[j1];
    }
    float w66pl[2][8];
#pragma unroll
    for (int ks = 0; ks < 2; ++ks)
#pragma unroll
        for (int jj = 0; jj < 8; ++jj)
            w66pl[ks][jj] = S.vec[384 + ks * 32 + q * 8 + jj];
    float b2pl[4][4], w3pl[4][4], cwpl[4][4];
#pragma unroll
    for (int mt = 0; mt < 4; ++mt)
#pragma unroll
        for (int e = 0; e < 4; ++e) {
            b2pl[mt][e] = S.vec[64 + mt * 16 + q * 4 + e];
            w3pl[mt][e] = S.vec[128 + mt * 16 + q * 4 + e];
            cwpl[mt][e] = S.vec[192 + mt * 16 + q * 4 + e];
        }

#pragma unroll 1
    for (int iter = 0; iter < 2; ++iter) {
        const int n0 = n0base + iter * 4;
        {
            int ss = t >> 7, nl = (t >> 5) & 3, k = t & 31;
            int n = n0 + nl;
            int a = ((b * 2 + ss) * 32 + (n >> 5)) * 63 + (n & 31) + k;
            S.flow[t] = flow[a];
            S.epi[t]  = lf[a];
        }
        __syncthreads();

        // ---- layer 1 ----
#pragma unroll
        for (int mt = 0; mt < 4; ++mt) {
            const int rbase = w * 64 + mt * 16;
            FragU af[2];
            {
                int r = rbase + l15;
                int n = n0 + ((r >> 5) & 3);
                int pos = (n >> 5) * 63 + (n & 31) + (r & 31);
                const u16* fp = feat + ((size_t)bsw * 2016 + pos) * 64;
                af[0] = *(const FragU*)(fp + q * 8);
                af[1] = *(const FragU*)(fp + 32 + q * 8);
            }
            f32x4 flow4 = *(const f32x4*)(S.flow + rbase + q * 4);
#pragma unroll
            for (int nt = 0; nt < 4; ++nt) {
                f32x4 d = {0.f, 0.f, 0.f, 0.f};
                d = __builtin_amdgcn_mfma_f32_16x16x32_bf16(af[0].v, w1b[0][nt].v, d, 0, 0, 0);
                d = __builtin_amdgcn_mfma_f32_16x16x32_bf16(af[1].v, w1b[1][nt].v, d, 0, 0, 0);
#pragma unroll
                for (int e = 0; e < 4; ++e) {
                    int r = rbase + q * 4 + e;
                    int k = r & 31;
                    float val = d[e] + flow4[e] * w1r0pl[nt]
                              + (float)(k - 16) * w1r65pl[nt] + b1pl[nt];
                    S.base[r * SBS + nt * 16 + l15] = f2bf(val);
                }
            }
        }
        __syncthreads();

        float epi_pl[4];
#pragma unroll
        for (int nt = 0; nt < 4; ++nt) epi_pl[nt] = S.epi[w * 64 + nt * 16 + l15];

        // ---- per-view loop ----
        for (int v = 0; v < 7; ++v) {
            float ang = (sw == 0) ? -(float)(v + 1) : (float)(7 - v);
            f32x4 acc[4][4];
#pragma unroll
            for (int nt = 0; nt < 4; ++nt) {
                FragU bfr[2]; // B = h1^T
#pragma unroll
                for (int ks = 0; ks < 2; ++ks) {
                    const u16x8 raw = *(const u16x8*)(S.base + (w * 64 + nt * 16 + l15) * SBS + ks * 32 + q * 8);
#pragma unroll
                    for (int jj = 0; jj < 8; ++jj) {
                        float xv = bf2f(raw[jj]);
                        float hv = fmaxf(xv + ang * w66pl[ks][jj], 0.f);
                        bfr[ks].u[jj] = f2bf(hv);
                    }
                }
#pragma unroll
                for (int mt = 0; mt < 4; ++mt) {
                    f32x4 d = {0.f, 0.f, 0.f, 0.f};
                    d = __builtin_amdgcn_mfma_f32_16x16x32_bf16(w2a[mt][0].v, bfr[0].v, d, 0, 0, 0);
                    d = __builtin_amdgcn_mfma_f32_16x16x32_bf16(w2a[mt][1].v, bfr[1].v, d, 0, 0, 0);
                    acc[mt][nt] = d;
                }
            }
            float wl[4], cfl[4];
#pragma unroll
            for (int nt = 0; nt < 4; ++nt) {
                float wls = 0.f, cfs = 0.f;
#pragma unroll
                for (int mt = 0; mt < 4; ++mt)
#pragma unroll
                    for (int e = 0; e < 4; ++e) {
                        float h2 = fmaxf(acc[mt][nt][e] + b2pl[mt][e], 0.f);
                        wls += h2 * w3pl[mt][e];
                        cfs += h2 * cwpl[mt][e];
                    }
                wls += __shfl_xor(wls, 16); wls += __shfl_xor(wls, 32);
                cfs += __shfl_xor(cfs, 16); cfs += __shfl_xor(cfs, 32);
                wl[nt]  = wls + b3s;
                cfl[nt] = cfs;
            }
#pragma unroll
            for (int ni = 0; ni < 2; ++ni) {
                float a0 = wl[ni * 2], a1 = wl[ni * 2 + 1];
                float mx = fmaxf(a0, a1);
#pragma unroll
                for (int msk = 1; msk <= 8; msk <<= 1) mx = fmaxf(mx, __shfl_xor(mx, msk));
                float e0 = __expf(a0 - mx), e1 = __expf(a1 - mx);
                float ssum = e0 + e1;
                float nvp = e0 * epi_pl[ni * 2] + e1 * epi_pl[ni * 2 + 1];
                float cfp = cfl[ni * 2] + cfl[ni * 2 + 1];
#pragma unroll
                for (int msk = 1; msk <= 8; msk <<= 1) {
                    ssum += __shfl_xor(ssum, msk);
                    nvp  += __shfl_xor(nvp, msk);
                    cfp  += __shfl_xor(cfp, msk);
                }
                if (lane == 0) {
                    int nloc = (w & 1) * 2 + ni;
                    S.nv[sw][v][nloc] = nvp / ssum;
                    S.cf[sw][v][nloc] = cfp * (1.f / 32.f) + cbs;
                }
            }
        }
        __syncthreads();

        // ---- conf softmax over s + write novel ----
        if (t < 28) {
            int v = t >> 2, nl = t & 3;
            float c0 = S.cf[0][v][nl], c1 = S.cf[1][v][nl];
            float mx = fmaxf(c0, c1);
            float e0 = __expf(c0 - mx), e1 = __expf(c1 - mx);
            novel[(size_t)(b * 7 + v) * 1024 + n0 + nl] =
                (e0 * S.nv[0][v][nl] + e1 * S.nv[1][v][nl]) / (e0 + e1);
        }
        // next iter's S.flow/S.epi writes don't alias S.nv/S.cf reads; the
        // sync after the flow write orders everything else.
    }
}

// ---------------- the fused persistent kernel -----------------------------
__global__ __launch_bounds__(256, 1) void fused_kernel(
    const float* __restrict__ lf, const float* __restrict__ flow,
    const float* __restrict__ wp, const float* __restrict__ pl,
    const float* __restrict__ pr,
    const float* __restrict__ frw1, const float* __restrict__ frb1,
    const float* __restrict__ frw2, const float* __restrict__ frb2,
    const float* __restrict__ frw3, const float* __restrict__ frb3,
    const float* __restrict__ mw1, const float* __restrict__ mb1,
    const float* __restrict__ mw2, const float* __restrict__ mb2,
    const float* __restrict__ mw3, const float* __restrict__ mb3,
    const float* __restrict__ cwp, const float* __restrict__ cbp,
    const float* __restrict__ vrw1, const float* __restrict__ vrb1,
    const float* __restrict__ vrw2, const float* __restrict__ vrb2,
    const float* __restrict__ vrw3, const float* __restrict__ vrb3,
    float* __restrict__ ws, float* __restrict__ out)
{
    __shared__ SharedU sh;
    u32* bar = (u32*)(ws + BARS);
    const int blk = blockIdx.x;
    const int t = threadIdx.x;

    // S1: feature conv1 (3->64), 256 units
    {
        int cg = blk & 7, pt = (blk >> 3) & 7, m = blk >> 6;
        conv3_unit<8>(flow, lf, wp, frw1, frb1, ws + FEAT_A, 32, 63,
                      cg * 8, pt * 256 + t, m, 64);
    }
    gbar(bar, 0);

    // S2: feature conv2 (64->64), 512 units
    for (int u = blk; u < 512; u += 256) {
        int cg = u & 31, pt = (u >> 5) & 3, m = u >> 7;
        conv64_unit<0>(ws + FEAT_A, frw2, frb2, ws + FEAT_B, nullptr,
                       32, 63, 32, 64, cg * 2, pt * 256 + t, m);
    }
    gbar(bar, 1);

    // S3: feature conv3 -> bf16 [bs][pos][64], 512 units
    for (int u = blk; u < 512; u += 256) {
        int cg = u & 31, pt = (u >> 5) & 3, m = u >> 7;
        conv64_unit<1>(ws + FEAT_B, frw3, frb3, nullptr, (u16*)(ws + FEATBF),
                       32, 63, 32, 64, cg * 2, pt * 256 + t, m);
    }
    gbar(bar, 2);

    // S4: MFMA MLP + softmax + epi + conf-combine -> novel
    mlp_stage(sh.mlp, lf, flow, (const u16*)(ws + FEATBF),
              mw1, mb1, mw2, mb2, mw3, mb3, cwp, cbp, ws + NOVEL, blk, t);
    gbar(bar, 3);

    // S5: refinement conv1 (3->64), 448 units
    for (int u = blk; u < 448; u += 256) {
        int cg = u & 7, pt = (u >> 3) & 3, m = u >> 5;
        conv3_unit<8>(ws + NOVEL, pl, pr, vrw1, vrb1, ws + FEAT_A, 32, 32,
                      cg * 8, pt * 256 + t, m, 64);
    }
    gbar(bar, 4);

    // S6: refinement conv2 (64->64), 896 units
    for (int u = blk; u < 896; u += 256) {
        int cg = u & 31, pt = (u >> 5) & 1, m = u >> 6;
        conv64_unit<0>(ws + FEAT_A, vrw2, vrb2, ws + FEAT_B, nullptr,
                       32, 32, 16, 64, cg * 2, pt * 256 + t, m);
    }
    gbar(bar, 5);

    // S7: final 64->1 conv + bias + residual, 224 units
    if (blk < 224) {
        int x16 = blk & 15, m = blk >> 4;
        convlast_unit(ws + FEAT_B, vrw3, vrb3, ws + NOVEL, out, x16, m, sh.red, t);
    }
}

// ---------------- launch ----------------
extern "C" void kernel_launch(void* const* d_in, const int* in_sizes, int n_in,
                              void* d_out, int out_size, void* d_ws, size_t ws_size,
                              hipStream_t stream) {
    const float* lf   = (const float*)d_in[0];
    const float* flow = (const float*)d_in[1];
    const float* wp   = (const float*)d_in[2];
    const float* pl   = (const float*)d_in[3];
    const float* pr   = (const float*)d_in[4];
    float* ws = (float*)d_ws;

    init_kernel<<<1, 64, 0, stream>>>((u32*)(ws + BARS));
    fused_kernel<<<256, 256, 0, stream>>>(
        lf, flow, wp, pl, pr,
        (const float*)d_in[5],  (const float*)d_in[6],
        (const float*)d_in[7],  (const float*)d_in[8],
        (const float*)d_in[9],  (const float*)d_in[10],
        (const float*)d_in[11], (const float*)d_in[12],
        (const float*)d_in[13], (const float*)d_in[14],
        (const float*)d_in[15], (const float*)d_in[16],
        (const float*)d_in[17], (const float*)d_in[18],
        (const float*)d_in[19], (const float*)d_in[20],
        (const float*)d_in[21], (const float*)d_in[22],
        (const float*)d_in[23], (const float*)d_in[24],
        ws, (float*)d_out);
}

// Round 7
// 482.811 us; speedup vs baseline: 1.2388x; 1.2388x over previous
//
#include <hip/hip_runtime.h>

typedef unsigned short u16;
typedef unsigned int u32;
typedef __bf16 bf16x8 __attribute__((ext_vector_type(8)));
typedef float f32x4 __attribute__((ext_vector_type(4)));
typedef u16 u16x8 __attribute__((ext_vector_type(8)));

__device__ __forceinline__ u16 f2bf(float f) {
    __bf16 h = (__bf16)f;
    return __builtin_bit_cast(u16, h);
}
__device__ __forceinline__ float bf2f(u16 u) {
    unsigned int x = ((unsigned int)u) << 16;
    return __builtin_bit_cast(float, x);
}

union FragU { u16x8 u; bf16x8 v; };

// ---------------- workspace layout (float offsets) ----------------
constexpr size_t FEATBF = 0;        // 258048 floats = 516096 u16 : [bs][2016][64]
constexpr size_t NVOFF  = 258048;   // 28672 : [(b*7+v)*2+s][1024]
constexpr size_t CFOFF  = 286720;   // 28672

// ================= D1: fused feature net, one block per (bs, row h) =======
// 512 thr. conv1 rows h-2..h+2 ring-buffered (3 slots) in LDS bf16;
// conv2 rows h-1..h+1 -> c2; conv3 row h -> featbf global bf16 [bs][pos][64].
// LDS tiles are [row][colidx 0..65 = col -1..64][ch 68pad] so the conv2/3
// inner loop is u16x8 reads (16B aligned, 2-way banks) + wave-uniform weights.
__global__ __launch_bounds__(512, 1) void feat3_kernel(
    const float* __restrict__ flow, const float* __restrict__ lf,
    const float* __restrict__ wp,
    const float* __restrict__ frw1, const float* __restrict__ frb1,
    const float* __restrict__ frw2, const float* __restrict__ frb2,
    const float* __restrict__ frw3, const float* __restrict__ frb3,
    u16* __restrict__ featbf)
{
    __shared__ u16 c1[3][66][68];
    __shared__ u16 c2[3][66][68];
    __shared__ float w1l[1728];
    __shared__ float b1l[64];

    const int t = threadIdx.x;
    const int bs = blockIdx.x >> 5;
    const int h  = blockIdx.x & 31;
    const int w  = t >> 6;
    const int lane = t & 63;
    const int og = __builtin_amdgcn_readfirstlane(w);  // wave-uniform och-group

    for (int i = t; i < 1728; i += 512) w1l[i] = frw1[i];
    if (t < 64) b1l[t] = frb1[t];
    {
        u32* z1 = (u32*)&c1[0][0][0];
        u32* z2 = (u32*)&c2[0][0][0];
        for (int i = t; i < 3 * 66 * 34; i += 512) { z1[i] = 0u; z2[i] = 0u; }
    }
    __syncthreads();

    for (int r5i = 0; r5i < 5; ++r5i) {
        const int gr = h - 2 + r5i;               // conv1 output row
        const int slot = (r5i >= 3) ? (r5i - 3) : r5i;  // r5i % 3
        if (gr >= 0 && gr < 32) {
            if (t < 504) {
                const int og1 = t / 63;
                const int col = t - og1 * 63;
                float acc[8];
#pragma unroll
                for (int oc = 0; oc < 8; ++oc) acc[oc] = b1l[og1 * 8 + oc];
#pragma unroll
                for (int cin = 0; cin < 3; ++cin) {
                    const float* ip = (cin == 0 ? flow : (cin == 1 ? lf : wp))
                                      + (size_t)bs * 32 * 63;
                    float tap[9];
#pragma unroll
                    for (int dy = 0; dy < 3; ++dy) {
                        int gy = gr + dy - 1;
                        bool ry = (gy >= 0) && (gy < 32);
#pragma unroll
                        for (int dx = 0; dx < 3; ++dx) {
                            int gx = col + dx - 1;
                            tap[dy * 3 + dx] = (ry && gx >= 0 && gx < 63)
                                             ? ip[gy * 63 + gx] : 0.f;
                        }
                    }
#pragma unroll
                    for (int oc = 0; oc < 8; ++oc) {
                        const float* wr = w1l + (og1 * 8 + oc) * 27 + cin * 9;
#pragma unroll
                        for (int j = 0; j < 9; ++j) acc[oc] = fmaf(tap[j], wr[j], acc[oc]);
                    }
                }
                u16x8 pk;
#pragma unroll
                for (int oc = 0; oc < 8; ++oc) pk[oc] = f2bf(fmaxf(acc[oc], 0.f));
                *(u16x8*)&c1[slot][col + 1][og1 * 8] = pk;
            }
        } else {
            // ring-slot reuse with out-of-range row: must be zero
            u32* z = (u32*)&c1[slot][0][0];
            for (int i = t; i < 66 * 34; i += 512) z[i] = 0u;
        }
        __syncthreads();

        if (r5i >= 2) {
            const int r3i = r5i - 2;              // c2 row 0..2
            const int gro = h - 1 + r3i;          // conv2 output row
            if (gro >= 0 && gro < 32 && lane < 63) {
                const int col = lane;
                float acc[8];
#pragma unroll
                for (int oc = 0; oc < 8; ++oc) acc[oc] = frb2[og * 8 + oc];
#pragma unroll 1
                for (int tap = 0; tap < 9; ++tap) {
                    const int dy = tap / 3, dx = tap - dy * 3;
                    int sl = r3i + dy; if (sl >= 3) sl -= 3;
                    const u16* src = &c1[sl][col + dx][0];
#pragma unroll
                    for (int cg = 0; cg < 8; ++cg) {
                        u16x8 raw = *(const u16x8*)(src + cg * 8);
                        float iv[8];
#pragma unroll
                        for (int e = 0; e < 8; ++e) iv[e] = bf2f(raw[e]);
#pragma unroll
                        for (int oc = 0; oc < 8; ++oc) {
                            const float* wr = frw2 + (size_t)(og * 8 + oc) * 576 + tap;
#pragma unroll
                            for (int e = 0; e < 8; ++e)
                                acc[oc] = fmaf(iv[e], wr[(cg * 8 + e) * 9], acc[oc]);
                        }
                    }
                }
                u16x8 pk;
#pragma unroll
                for (int oc = 0; oc < 8; ++oc) pk[oc] = f2bf(fmaxf(acc[oc], 0.f));
                *(u16x8*)&c2[r3i][col + 1][og * 8] = pk;
            }
            __syncthreads();
        }
    }

    // conv3 (row h) -> featbf
    if (lane < 63) {
        const int col = lane;
        float acc[8];
#pragma unroll
        for (int oc = 0; oc < 8; ++oc) acc[oc] = frb3[og * 8 + oc];
#pragma unroll 1
        for (int tap = 0; tap < 9; ++tap) {
            const int dy = tap / 3, dx = tap - dy * 3;
            const u16* src = &c2[dy][col + dx][0];
#pragma unroll
            for (int cg = 0; cg < 8; ++cg) {
                u16x8 raw = *(const u16x8*)(src + cg * 8);
                float iv[8];
#pragma unroll
                for (int e = 0; e < 8; ++e) iv[e] = bf2f(raw[e]);
#pragma unroll
                for (int oc = 0; oc < 8; ++oc) {
                    const float* wr = frw3 + (size_t)(og * 8 + oc) * 576 + tap;
#pragma unroll
                    for (int e = 0; e < 8; ++e)
                        acc[oc] = fmaf(iv[e], wr[(cg * 8 + e) * 9], acc[oc]);
                }
            }
        }
        u16x8 pk;
#pragma unroll
        for (int oc = 0; oc < 8; ++oc) pk[oc] = f2bf(fmaxf(acc[oc], 0.f));
        *(u16x8*)(featbf + ((size_t)(bs * 2016 + h * 63 + col)) * 64 + og * 8) = pk;
    }
}

// ================= D2: MFMA MLP (round-4 verified body, r5 feat layout) ====
__global__ __launch_bounds__(256, 2) void mlp_mfma_kernel(
    const float* __restrict__ lf, const float* __restrict__ flow,
    const u16* __restrict__ feat,   // [bs][2016][64] bf16
    const float* __restrict__ w1, const float* __restrict__ b1,
    const float* __restrict__ w2, const float* __restrict__ b2,
    const float* __restrict__ w3, const float* __restrict__ b3g,
    const float* __restrict__ cw, const float* __restrict__ cbg,
    float* __restrict__ nv_out, float* __restrict__ cf_out)
{
    constexpr int SBS = 72;
    __shared__ u16 s_w1[67 * 64];
    __shared__ u16 s_w2[64 * 64];
    __shared__ __align__(16) float s_vec[7 * 64];
    __shared__ __align__(16) float s_flow[256];
    __shared__ __align__(16) float s_epi[256];
    __shared__ __align__(16) u16 s_base[256 * SBS];

    const int t = threadIdx.x;
    const int blk = blockIdx.x;
    const int bs = blk >> 7;
    const int n0 = (blk & 127) * 8;
    const int b = bs >> 1, s = bs & 1;
    const int w = t >> 6, lane = t & 63, q = lane >> 4, l15 = lane & 15;

    for (int i = t; i < 67 * 64; i += 256) s_w1[i] = f2bf(w1[i]);
    for (int i = t; i < 64 * 64; i += 256) s_w2[i] = f2bf(w2[i]);
    if (t < 64) {
        s_vec[t]       = b1[t];
        s_vec[64 + t]  = b2[t];
        s_vec[128 + t] = w3[t];
        s_vec[192 + t] = cw[t];
        s_vec[256 + t] = w1[t];
        s_vec[320 + t] = w1[65 * 64 + t];
        s_vec[384 + t] = w1[66 * 64 + t];
    }
    {
        int nl = t >> 5, k = t & 31;
        int n = n0 + nl;
        int a = (bs * 32 + (n >> 5)) * 63 + (n & 31) + k;
        s_flow[t] = flow[a];
        s_epi[t]  = lf[a];
    }
    __syncthreads();

    const float b3s = b3g[0];
    const float cbs = cbg[0];

    FragU w1b[2][4];
#pragma unroll
    for (int ks = 0; ks < 2; ++ks)
#pragma unroll
        for (int nt = 0; nt < 4; ++nt)
#pragma unroll
            for (int jj = 0; jj < 8; ++jj)
                w1b[ks][nt].u[jj] = s_w1[(1 + ks * 32 + q * 8 + jj) * 64 + nt * 16 + l15];

    float w1r0pl[4], w1r65pl[4], b1pl[4];
#pragma unroll
    for (int nt = 0; nt < 4; ++nt) {
        int j1 = nt * 16 + l15;
        w1r0pl[nt]  = s_vec[256 + j1];
        w1r65pl[nt] = s_vec[320 + j1];
        b1pl[nt]    = s_vec[j1];
    }

#pragma unroll
    for (int mt = 0; mt < 4; ++mt) {
        const int rbase = w * 64 + mt * 16;
        FragU af[2];
        {
            int r = rbase + l15;
            int n = n0 + (r >> 5);
            int pos = (n >> 5) * 63 + (n & 31) + (r & 31);
            const u16* fp = feat + ((size_t)bs * 2016 + pos) * 64;
            af[0] = *(const FragU*)(fp + q * 8);
            af[1] = *(const FragU*)(fp + 32 + q * 8);
        }
        f32x4 flow4 = *(const f32x4*)(s_flow + rbase + q * 4);
#pragma unroll
        for (int nt = 0; nt < 4; ++nt) {
            f32x4 d = {0.f, 0.f, 0.f, 0.f};
            d = __builtin_amdgcn_mfma_f32_16x16x32_bf16(af[0].v, w1b[0][nt].v, d, 0, 0, 0);
            d = __builtin_amdgcn_mfma_f32_16x16x32_bf16(af[1].v, w1b[1][nt].v, d, 0, 0, 0);
#pragma unroll
            for (int e = 0; e < 4; ++e) {
                int r = rbase + q * 4 + e;
                int k = r & 31;
                float val = d[e] + flow4[e] * w1r0pl[nt]
                          + (float)(k - 16) * w1r65pl[nt] + b1pl[nt];
                s_base[r * SBS + nt * 16 + l15] = f2bf(val);
            }
        }
    }
    __syncthreads();

    FragU w2a[4][2];
#pragma unroll
    for (int mt = 0; mt < 4; ++mt)
#pragma unroll
        for (int ks = 0; ks < 2; ++ks)
#pragma unroll
            for (int jj = 0; jj < 8; ++jj)
                w2a[mt][ks].u[jj] = s_w2[(ks * 32 + q * 8 + jj) * 64 + mt * 16 + l15];

    float w66pl[2][8];
#pragma unroll
    for (int ks = 0; ks < 2; ++ks)
#pragma unroll
        for (int jj = 0; jj < 8; ++jj)
            w66pl[ks][jj] = s_vec[384 + ks * 32 + q * 8 + jj];

    float b2pl[4][4], w3pl[4][4], cwpl[4][4];
#pragma unroll
    for (int mt = 0; mt < 4; ++mt)
#pragma unroll
        for (int e = 0; e < 4; ++e) {
            b2pl[mt][e] = s_vec[64 + mt * 16 + q * 4 + e];
            w3pl[mt][e] = s_vec[128 + mt * 16 + q * 4 + e];
            cwpl[mt][e] = s_vec[192 + mt * 16 + q * 4 + e];
        }
    float epi_pl[4];
#pragma unroll
    for (int nt = 0; nt < 4; ++nt) epi_pl[nt] = s_epi[w * 64 + nt * 16 + l15];

    for (int v = 0; v < 7; ++v) {
        float ang = (s == 0) ? -(float)(v + 1) : (float)(7 - v);
        f32x4 acc[4][4];
#pragma unroll
        for (int nt = 0; nt < 4; ++nt) {
            FragU bfr[2];
#pragma unroll
            for (int ks = 0; ks < 2; ++ks) {
                const u16x8 raw = *(const u16x8*)(s_base + (w * 64 + nt * 16 + l15) * SBS + ks * 32 + q * 8);
#pragma unroll
                for (int jj = 0; jj < 8; ++jj) {
                    float xv = bf2f(raw[jj]);
                    float hv = fmaxf(xv + ang * w66pl[ks][jj], 0.f);
                    bfr[ks].u[jj] = f2bf(hv);
                }
            }
#pragma unroll
            for (int mt = 0; mt < 4; ++mt) {
                f32x4 d = {0.f, 0.f, 0.f, 0.f};
                d = __builtin_amdgcn_mfma_f32_16x16x32_bf16(w2a[mt][0].v, bfr[0].v, d, 0, 0, 0);
                d = __builtin_amdgcn_mfma_f32_16x16x32_bf16(w2a[mt][1].v, bfr[1].v, d, 0, 0, 0);
                acc[mt][nt] = d;
            }
        }
        float wl[4], cfl[4];
#pragma unroll
        for (int nt = 0; nt < 4; ++nt) {
            float wls = 0.f, cfs = 0.f;
#pragma unroll
            for (int mt = 0; mt < 4; ++mt)
#pragma unroll
                for (int e = 0; e < 4; ++e) {
                    float h2 = fmaxf(acc[mt][nt][e] + b2pl[mt][e], 0.f);
                    wls += h2 * w3pl[mt][e];
                    cfs += h2 * cwpl[mt][e];
                }
            wls += __shfl_xor(wls, 16); wls += __shfl_xor(wls, 32);
            cfs += __shfl_xor(cfs, 16); cfs += __shfl_xor(cfs, 32);
            wl[nt]  = wls + b3s;
            cfl[nt] = cfs;
        }
#pragma unroll
        for (int ni = 0; ni < 2; ++ni) {
            float a0 = wl[ni * 2], a1 = wl[ni * 2 + 1];
            float mx = fmaxf(a0, a1);
#pragma unroll
            for (int msk = 1; msk <= 8; msk <<= 1) mx = fmaxf(mx, __shfl_xor(mx, msk));
            float e0 = __expf(a0 - mx), e1 = __expf(a1 - mx);
            float ssum = e0 + e1;
            float nvp = e0 * epi_pl[ni * 2] + e1 * epi_pl[ni * 2 + 1];
            float cfp = cfl[ni * 2] + cfl[ni * 2 + 1];
#pragma unroll
            for (int msk = 1; msk <= 8; msk <<= 1) {
                ssum += __shfl_xor(ssum, msk);
                nvp  += __shfl_xor(nvp, msk);
                cfp  += __shfl_xor(cfp, msk);
            }
            if (lane == 0) {
                int n = n0 + w * 2 + ni;
                size_t idx = ((size_t)(b * 7 + v) * 2 + s) * 1024 + n;
                nv_out[idx] = nvp / ssum;
                cf_out[idx] = cfp * (1.f / 32.f) + cbs;
            }
        }
    }
}

// ================= D3: fused refinement, one block per (bv, 2-row band) ====
__global__ __launch_bounds__(512, 1) void refine_kernel(
    const float* __restrict__ nv, const float* __restrict__ cf,
    const float* __restrict__ pl, const float* __restrict__ pr,
    const float* __restrict__ vrw1, const float* __restrict__ vrb1,
    const float* __restrict__ vrw2, const float* __restrict__ vrb2,
    const float* __restrict__ vrw3, const float* __restrict__ vrb3,
    float* __restrict__ out)
{
    __shared__ u16 n1[6][34][68];
    __shared__ u16 n2[4][34][68];
    __shared__ float w1l[1728];
    __shared__ float b1l[64];
    __shared__ float w3l[576];
    __shared__ float nov[8][32];
    __shared__ float red[256];

    const int t = threadIdx.x;
    const int bv = blockIdx.x >> 4;      // 0..13
    const int band = blockIdx.x & 15;
    const int r0 = band * 2;
    const int w = t >> 6, lane = t & 63;
    const int og = __builtin_amdgcn_readfirstlane(w);

    for (int i = t; i < 1728; i += 512) w1l[i] = vrw1[i];
    if (t < 64) b1l[t] = vrb1[t];
    for (int i = t; i < 576; i += 512) w3l[i] = vrw3[i];
    {
        u32* z1 = (u32*)&n1[0][0][0];
        u32* z2 = (u32*)&n2[0][0][0];
        for (int i = t; i < 6 * 34 * 34; i += 512) z1[i] = 0u;
        for (int i = t; i < 4 * 34 * 34; i += 512) z2[i] = 0u;
    }
    // novel rows r0-3 .. r0+4 via conf-combine (round-4 combine math)
    if (t < 256) {
        int ri = t >> 5, col = t & 31;
        int gr = r0 - 3 + ri;
        float vv = 0.f;
        if (gr >= 0 && gr < 32) {
            int n = gr * 32 + col;
            size_t i0 = ((size_t)bv * 2 + 0) * 1024 + n;
            size_t i1 = ((size_t)bv * 2 + 1) * 1024 + n;
            float c0 = cf[i0], c1v = cf[i1];
            float mx = fmaxf(c0, c1v);
            float e0 = __expf(c0 - mx), e1 = __expf(c1v - mx);
            vv = (e0 * nv[i0] + e1 * nv[i1]) / (e0 + e1);
        }
        nov[ri][col] = vv;
    }
    __syncthreads();

    // conv1: rows gout = r0-2 .. r0+3 (6 rows), 1536 tasks, 3 rounds
#pragma unroll 1
    for (int rnd = 0; rnd < 3; ++rnd) {
        int task = rnd * 512 + t;
        int or1 = task >> 8;
        int rem = task & 255;
        int og1 = rem >> 5, col = rem & 31;
        int gout = r0 - 2 + or1;
        if (gout >= 0 && gout < 32) {
            float acc[8];
#pragma unroll
            for (int oc = 0; oc < 8; ++oc) acc[oc] = b1l[og1 * 8 + oc];
#pragma unroll
            for (int cin = 0; cin < 3; ++cin) {
                float tap[9];
#pragma unroll
                for (int dy = 0; dy < 3; ++dy) {
                    int gy = gout + dy - 1;
                    bool ry = (gy >= 0) && (gy < 32);
#pragma unroll
                    for (int dx = 0; dx < 3; ++dx) {
                        int gx = col + dx - 1;
                        bool ok = ry && (gx >= 0) && (gx < 32);
                        float vv = 0.f;
                        if (ok) {
                            if (cin == 0) vv = nov[or1 + dy][gx];
                            else if (cin == 1) vv = pl[(size_t)bv * 1024 + gy * 32 + gx];
                            else vv = pr[(size_t)bv * 1024 + gy * 32 + gx];
                        }
                        tap[dy * 3 + dx] = vv;
                    }
                }
#pragma unroll
                for (int oc = 0; oc < 8; ++oc) {
                    const float* wr = w1l + (og1 * 8 + oc) * 27 + cin * 9;
#pragma unroll
                    for (int j = 0; j < 9; ++j) acc[oc] = fmaf(tap[j], wr[j], acc[oc]);
                }
            }
            u16x8 pk;
#pragma unroll
            for (int oc = 0; oc < 8; ++oc) pk[oc] = f2bf(fmaxf(acc[oc], 0.f));
            *(u16x8*)&n1[or1][col + 1][og1 * 8] = pk;
        }
    }
    __syncthreads();

    // conv2: rows gr2 = r0-1+or2, or2 = inner*2 + (lane>>5); wave-uniform og
    {
        const int sub = lane >> 5;
        const int col = lane & 31;
#pragma unroll 1
        for (int inner = 0; inner < 2; ++inner) {
            const int or2 = inner * 2 + sub;
            const int gr2 = r0 - 1 + or2;
            if (gr2 >= 0 && gr2 < 32) {
                float acc[8];
#pragma unroll
                for (int oc = 0; oc < 8; ++oc) acc[oc] = vrb2[og * 8 + oc];
#pragma unroll 1
                for (int tap = 0; tap < 9; ++tap) {
                    const int dy = tap / 3, dx = tap - dy * 3;
                    const u16* src = &n1[or2 + dy][col + dx][0];
#pragma unroll
                    for (int cg = 0; cg < 8; ++cg) {
                        u16x8 raw = *(const u16x8*)(src + cg * 8);
                        float iv[8];
#pragma unroll
                        for (int e = 0; e < 8; ++e) iv[e] = bf2f(raw[e]);
#pragma unroll
                        for (int oc = 0; oc < 8; ++oc) {
                            const float* wr = vrw2 + (size_t)(og * 8 + oc) * 576 + tap;
#pragma unroll
                            for (int e = 0; e < 8; ++e)
                                acc[oc] = fmaf(iv[e], wr[(cg * 8 + e) * 9], acc[oc]);
                        }
                    }
                }
                u16x8 pk;
#pragma unroll
                for (int oc = 0; oc < 8; ++oc) pk[oc] = f2bf(fmaxf(acc[oc], 0.f));
                *(u16x8*)&n2[or2][col + 1][og * 8] = pk;
            }
        }
    }
    __syncthreads();

    // conv3 (64->1) + bias + residual: rows r0, r0+1 (64 px, 4-way cin split)
    float a = 0.f;
    if (t < 256) {
        const int px = t >> 2;
        const int q4 = t & 3;
        const int ri = px >> 5, col = px & 31;
#pragma unroll
        for (int dy = 0; dy < 3; ++dy) {
            const int r2i = ri + dy;
#pragma unroll
            for (int dx = 0; dx < 3; ++dx) {
                const u16* src = &n2[r2i][col + dx][q4 * 16];
#pragma unroll
                for (int cg = 0; cg < 2; ++cg) {
                    u16x8 raw = *(const u16x8*)(src + cg * 8);
#pragma unroll
                    for (int e = 0; e < 8; ++e)
                        a = fmaf(bf2f(raw[e]),
                                 w3l[(q4 * 16 + cg * 8 + e) * 9 + dy * 3 + dx], a);
                }
            }
        }
        red[t] = a;
    }
    __syncthreads();
    if (t < 64) {
        const int ri = t >> 5, col = t & 31;
        float vv = red[t * 4] + red[t * 4 + 1] + red[t * 4 + 2] + red[t * 4 + 3]
                 + vrb3[0] + nov[ri + 3][col];
        out[(size_t)bv * 1024 + (r0 + ri) * 32 + col] = vv;
    }
}

// ---------------- launch ----------------
extern "C" void kernel_launch(void* const* d_in, const int* in_sizes, int n_in,
                              void* d_out, int out_size, void* d_ws, size_t ws_size,
                              hipStream_t stream) {
    const float* lf   = (const float*)d_in[0];
    const float* flow = (const float*)d_in[1];
    const float* wp   = (const float*)d_in[2];
    const float* pl   = (const float*)d_in[3];
    const float* pr   = (const float*)d_in[4];
    float* ws = (float*)d_ws;

    feat3_kernel<<<128, 512, 0, stream>>>(
        flow, lf, wp,
        (const float*)d_in[5],  (const float*)d_in[6],
        (const float*)d_in[7],  (const float*)d_in[8],
        (const float*)d_in[9],  (const float*)d_in[10],
        (u16*)(ws + FEATBF));

    mlp_mfma_kernel<<<512, 256, 0, stream>>>(
        lf, flow, (const u16*)(ws + FEATBF),
        (const float*)d_in[11], (const float*)d_in[12],
        (const float*)d_in[13], (const float*)d_in[14],
        (const float*)d_in[15], (const float*)d_in[16],
        (const float*)d_in[17], (const float*)d_in[18],
        ws + NVOFF, ws + CFOFF);

    refine_kernel<<<224, 512, 0, stream>>>(
        ws + NVOFF, ws + CFOFF, pl, pr,
        (const float*)d_in[19], (const float*)d_in[20],
        (const float*)d_in[21], (const float*)d_in[22],
        (const float*)d_in[23], (const float*)d_in[24],
        (float*)d_out);
}

// Round 8
// 201.293 us; speedup vs baseline: 2.9713x; 2.3986x over previous
//
#include <hip/hip_runtime.h>

typedef unsigned short u16;
typedef unsigned int u32;
typedef __bf16 bf16x8 __attribute__((ext_vector_type(8)));
typedef float f32x4 __attribute__((ext_vector_type(4)));
typedef u16 u16x8 __attribute__((ext_vector_type(8)));

__device__ __forceinline__ u16 f2bf(float f) {
    __bf16 h = (__bf16)f;
    return __builtin_bit_cast(u16, h);
}
__device__ __forceinline__ float bf2f(u16 u) {
    unsigned int x = ((unsigned int)u) << 16;
    return __builtin_bit_cast(float, x);
}

union FragU { u16x8 u; bf16x8 v; };

// ---------------- workspace layout (float offsets) ----------------
constexpr size_t X1     = 0;        // 258048 f = 4*2016*64 u16 (bf16, ch-last)
constexpr size_t X2     = 258048;   // 258048
constexpr size_t FEATBF = 516096;   // 258048
constexpr size_t NVOFF  = 774144;   // 28672
constexpr size_t CFOFF  = 802816;   // 28672
constexpr size_t NOVEL  = 831488;   // 14336
constexpr size_t Y1     = 845824;   // 458752 f = 14*1024*64 u16
constexpr size_t Y2     = 1304576;  // 458752
// total ~1763328 f = 7.05 MB (conv overreads of ~2K u16 land in the next buffer)

// ================= conv1: 3ch -> 64, VALU, ch-last bf16 out ===============
// TRIPLE inputs are single-channel f32 [M][NPX]. grid (8 og, pt, M), 256 thr.
template<int W, int NPX>
__global__ __launch_bounds__(256) void conv1_kernel(
    const float* __restrict__ in0, const float* __restrict__ in1,
    const float* __restrict__ in2,
    const float* __restrict__ wts, const float* __restrict__ bias,
    u16* __restrict__ out)
{
    constexpr int H = 32;
    const int t = threadIdx.x;
    const int px = blockIdx.y * 256 + t;
    const int m = blockIdx.z;
    const int og = blockIdx.x;
    if (px >= NPX) return;
    const int y = px / W, x = px - y * W;

    float acc[8];
#pragma unroll
    for (int oc = 0; oc < 8; ++oc) acc[oc] = bias[og * 8 + oc];

#pragma unroll
    for (int cin = 0; cin < 3; ++cin) {
        const float* ip = (cin == 0 ? in0 : (cin == 1 ? in1 : in2)) + (size_t)m * NPX;
        float tap[9];
#pragma unroll
        for (int dy = 0; dy < 3; ++dy) {
            int yy = y + dy - 1;
            bool ry = (yy >= 0) && (yy < H);
#pragma unroll
            for (int dx = 0; dx < 3; ++dx) {
                int xx = x + dx - 1;
                tap[dy * 3 + dx] = (ry && xx >= 0 && xx < W) ? ip[yy * W + xx] : 0.f;
            }
        }
#pragma unroll
        for (int oc = 0; oc < 8; ++oc) {
            const float* wr = wts + (size_t)(og * 8 + oc) * 27 + cin * 9;
#pragma unroll
            for (int j = 0; j < 9; ++j) acc[oc] = fmaf(tap[j], wr[j], acc[oc]);
        }
    }
    u16x8 pk;
#pragma unroll
    for (int oc = 0; oc < 8; ++oc) pk[oc] = f2bf(fmaxf(acc[oc], 0.f));
    *(u16x8*)(out + ((size_t)m * NPX + px) * 64 + og * 8) = pk;
}

// ================= convMFMA: 64ch -> 64ch 3x3 SAME, bf16 MFMA =============
// in/out ch-last bf16 [M][NPX][64]. W2 f32 [och][cin][9] staged to LDS bf16
// [tapLocal][och][cin] in two phases (taps 0-4, 5-8; 40KB). Block = 64-px
// m-tile x 64 och; wave w owns 16 px. A-frag = predicated 16B global load.
// Fragment maps match the verified MLP: A[m=l15][k=q*8+jj], B[k][n=l15],
// D row=q*4+e col=l15.
template<int W, int NPX>
__global__ __launch_bounds__(256) void convmfma_kernel(
    const u16* __restrict__ in, const float* __restrict__ wts,
    const float* __restrict__ bias, u16* __restrict__ out)
{
    constexpr int H = 32;
    __shared__ u16 sw[5 * 64 * 64];   // 40960 B

    const int t = threadIdx.x;
    const int base = blockIdx.x * 64;
    const int m = blockIdx.y;
    const int w = t >> 6, lane = t & 63, q = lane >> 4, l15 = lane & 15;

    const u16* im = in + (size_t)m * NPX * 64;
    const int pxA = base + w * 16 + l15;
    const int yA = pxA / W, xA = pxA - yA * W;
    const bool pxok = (pxA < NPX);

    f32x4 acc[4];
#pragma unroll
    for (int nt = 0; nt < 4; ++nt) acc[nt] = f32x4{0.f, 0.f, 0.f, 0.f};

#pragma unroll
    for (int phase = 0; phase < 2; ++phase) {
        const int tp0 = phase * 5;
        const int ntap = phase ? 4 : 5;
        if (phase) __syncthreads();   // protect LDS reuse
        for (int i = t; i < ntap * 4096; i += 256) {
            int tap = tp0 + (i >> 12), och = (i >> 6) & 63, cin = i & 63;
            sw[i] = f2bf(wts[(size_t)och * 576 + cin * 9 + tap]);
        }
        __syncthreads();
#pragma unroll
        for (int tl = 0; tl < 5; ++tl) {
            if (tl >= ntap) break;
            const int tap = tp0 + tl;
            const int dy = tap / 3 - 1, dx = tap % 3 - 1;
            const bool valid = pxok && (yA + dy >= 0) && (yA + dy < H)
                                    && (xA + dx >= 0) && (xA + dx < W);
            const u16* ap = im + (size_t)(pxA + dy * W + dx) * 64;
            FragU a0, a1;
            if (valid) {
                a0 = *(const FragU*)(ap + q * 8);
                a1 = *(const FragU*)(ap + 32 + q * 8);
            } else {
#pragma unroll
                for (int jj = 0; jj < 8; ++jj) { a0.u[jj] = 0; a1.u[jj] = 0; }
            }
#pragma unroll
            for (int nt = 0; nt < 4; ++nt) {
                const u16* bp = sw + tl * 4096 + (nt * 16 + l15) * 64;
                FragU b0 = *(const FragU*)(bp + q * 8);
                FragU b1 = *(const FragU*)(bp + 32 + q * 8);
                acc[nt] = __builtin_amdgcn_mfma_f32_16x16x32_bf16(a0.v, b0.v, acc[nt], 0, 0, 0);
                acc[nt] = __builtin_amdgcn_mfma_f32_16x16x32_bf16(a1.v, b1.v, acc[nt], 0, 0, 0);
            }
        }
    }

    // epilogue: + bias, relu, store ch-last
#pragma unroll
    for (int nt = 0; nt < 4; ++nt) {
        const float bb = bias[nt * 16 + l15];
#pragma unroll
        for (int e = 0; e < 4; ++e) {
            int pxs = base + w * 16 + q * 4 + e;
            if (pxs < NPX)
                out[((size_t)m * NPX + pxs) * 64 + nt * 16 + l15] =
                    f2bf(fmaxf(acc[nt][e] + bb, 0.f));
        }
    }
}

// ================= MLP (round-4/7 verified body) ===========================
__global__ __launch_bounds__(256, 2) void mlp_mfma_kernel(
    const float* __restrict__ lf, const float* __restrict__ flow,
    const u16* __restrict__ feat,   // [bs][2016][64] bf16
    const float* __restrict__ w1, const float* __restrict__ b1,
    const float* __restrict__ w2, const float* __restrict__ b2,
    const float* __restrict__ w3, const float* __restrict__ b3g,
    const float* __restrict__ cw, const float* __restrict__ cbg,
    float* __restrict__ nv_out, float* __restrict__ cf_out)
{
    constexpr int SBS = 72;
    __shared__ u16 s_w1[67 * 64];
    __shared__ u16 s_w2[64 * 64];
    __shared__ __align__(16) float s_vec[7 * 64];
    __shared__ __align__(16) float s_flow[256];
    __shared__ __align__(16) float s_epi[256];
    __shared__ __align__(16) u16 s_base[256 * SBS];

    const int t = threadIdx.x;
    const int blk = blockIdx.x;
    const int bs = blk >> 7;
    const int n0 = (blk & 127) * 8;
    const int b = bs >> 1, s = bs & 1;
    const int w = t >> 6, lane = t & 63, q = lane >> 4, l15 = lane & 15;

    for (int i = t; i < 67 * 64; i += 256) s_w1[i] = f2bf(w1[i]);
    for (int i = t; i < 64 * 64; i += 256) s_w2[i] = f2bf(w2[i]);
    if (t < 64) {
        s_vec[t]       = b1[t];
        s_vec[64 + t]  = b2[t];
        s_vec[128 + t] = w3[t];
        s_vec[192 + t] = cw[t];
        s_vec[256 + t] = w1[t];
        s_vec[320 + t] = w1[65 * 64 + t];
        s_vec[384 + t] = w1[66 * 64 + t];
    }
    {
        int nl = t >> 5, k = t & 31;
        int n = n0 + nl;
        int a = (bs * 32 + (n >> 5)) * 63 + (n & 31) + k;
        s_flow[t] = flow[a];
        s_epi[t]  = lf[a];
    }
    __syncthreads();

    const float b3s = b3g[0];
    const float cbs = cbg[0];

    FragU w1b[2][4];
#pragma unroll
    for (int ks = 0; ks < 2; ++ks)
#pragma unroll
        for (int nt = 0; nt < 4; ++nt)
#pragma unroll
            for (int jj = 0; jj < 8; ++jj)
                w1b[ks][nt].u[jj] = s_w1[(1 + ks * 32 + q * 8 + jj) * 64 + nt * 16 + l15];

    float w1r0pl[4], w1r65pl[4], b1pl[4];
#pragma unroll
    for (int nt = 0; nt < 4; ++nt) {
        int j1 = nt * 16 + l15;
        w1r0pl[nt]  = s_vec[256 + j1];
        w1r65pl[nt] = s_vec[320 + j1];
        b1pl[nt]    = s_vec[j1];
    }

#pragma unroll
    for (int mt = 0; mt < 4; ++mt) {
        const int rbase = w * 64 + mt * 16;
        FragU af[2];
        {
            int r = rbase + l15;
            int n = n0 + (r >> 5);
            int pos = (n >> 5) * 63 + (n & 31) + (r & 31);
            const u16* fp = feat + ((size_t)bs * 2016 + pos) * 64;
            af[0] = *(const FragU*)(fp + q * 8);
            af[1] = *(const FragU*)(fp + 32 + q * 8);
        }
        f32x4 flow4 = *(const f32x4*)(s_flow + rbase + q * 4);
#pragma unroll
        for (int nt = 0; nt < 4; ++nt) {
            f32x4 d = {0.f, 0.f, 0.f, 0.f};
            d = __builtin_amdgcn_mfma_f32_16x16x32_bf16(af[0].v, w1b[0][nt].v, d, 0, 0, 0);
            d = __builtin_amdgcn_mfma_f32_16x16x32_bf16(af[1].v, w1b[1][nt].v, d, 0, 0, 0);
#pragma unroll
            for (int e = 0; e < 4; ++e) {
                int r = rbase + q * 4 + e;
                int k = r & 31;
                float val = d[e] + flow4[e] * w1r0pl[nt]
                          + (float)(k - 16) * w1r65pl[nt] + b1pl[nt];
                s_base[r * SBS + nt * 16 + l15] = f2bf(val);
            }
        }
    }
    __syncthreads();

    FragU w2a[4][2];
#pragma unroll
    for (int mt = 0; mt < 4; ++mt)
#pragma unroll
        for (int ks = 0; ks < 2; ++ks)
#pragma unroll
            for (int jj = 0; jj < 8; ++jj)
                w2a[mt][ks].u[jj] = s_w2[(ks * 32 + q * 8 + jj) * 64 + mt * 16 + l15];

    float w66pl[2][8];
#pragma unroll
    for (int ks = 0; ks < 2; ++ks)
#pragma unroll
        for (int jj = 0; jj < 8; ++jj)
            w66pl[ks][jj] = s_vec[384 + ks * 32 + q * 8 + jj];

    float b2pl[4][4], w3pl[4][4], cwpl[4][4];
#pragma unroll
    for (int mt = 0; mt < 4; ++mt)
#pragma unroll
        for (int e = 0; e < 4; ++e) {
            b2pl[mt][e] = s_vec[64 + mt * 16 + q * 4 + e];
            w3pl[mt][e] = s_vec[128 + mt * 16 + q * 4 + e];
            cwpl[mt][e] = s_vec[192 + mt * 16 + q * 4 + e];
        }
    float epi_pl[4];
#pragma unroll
    for (int nt = 0; nt < 4; ++nt) epi_pl[nt] = s_epi[w * 64 + nt * 16 + l15];

    for (int v = 0; v < 7; ++v) {
        float ang = (s == 0) ? -(float)(v + 1) : (float)(7 - v);
        f32x4 acc[4][4];
#pragma unroll
        for (int nt = 0; nt < 4; ++nt) {
            FragU bfr[2];
#pragma unroll
            for (int ks = 0; ks < 2; ++ks) {
                const u16x8 raw = *(const u16x8*)(s_base + (w * 64 + nt * 16 + l15) * SBS + ks * 32 + q * 8);
#pragma unroll
                for (int jj = 0; jj < 8; ++jj) {
                    float xv = bf2f(raw[jj]);
                    float hv = fmaxf(xv + ang * w66pl[ks][jj], 0.f);
                    bfr[ks].u[jj] = f2bf(hv);
                }
            }
#pragma unroll
            for (int mt = 0; mt < 4; ++mt) {
                f32x4 d = {0.f, 0.f, 0.f, 0.f};
                d = __builtin_amdgcn_mfma_f32_16x16x32_bf16(w2a[mt][0].v, bfr[0].v, d, 0, 0, 0);
                d = __builtin_amdgcn_mfma_f32_16x16x32_bf16(w2a[mt][1].v, bfr[1].v, d, 0, 0, 0);
                acc[mt][nt] = d;
            }
        }
        float wl[4], cfl[4];
#pragma unroll
        for (int nt = 0; nt < 4; ++nt) {
            float wls = 0.f, cfs = 0.f;
#pragma unroll
            for (int mt = 0; mt < 4; ++mt)
#pragma unroll
                for (int e = 0; e < 4; ++e) {
                    float h2 = fmaxf(acc[mt][nt][e] + b2pl[mt][e], 0.f);
                    wls += h2 * w3pl[mt][e];
                    cfs += h2 * cwpl[mt][e];
                }
            wls += __shfl_xor(wls, 16); wls += __shfl_xor(wls, 32);
            cfs += __shfl_xor(cfs, 16); cfs += __shfl_xor(cfs, 32);
            wl[nt]  = wls + b3s;
            cfl[nt] = cfs;
        }
#pragma unroll
        for (int ni = 0; ni < 2; ++ni) {
            float a0 = wl[ni * 2], a1 = wl[ni * 2 + 1];
            float mx = fmaxf(a0, a1);
#pragma unroll
            for (int msk = 1; msk <= 8; msk <<= 1) mx = fmaxf(mx, __shfl_xor(mx, msk));
            float e0 = __expf(a0 - mx), e1 = __expf(a1 - mx);
            float ssum = e0 + e1;
            float nvp = e0 * epi_pl[ni * 2] + e1 * epi_pl[ni * 2 + 1];
            float cfp = cfl[ni * 2] + cfl[ni * 2 + 1];
#pragma unroll
            for (int msk = 1; msk <= 8; msk <<= 1) {
                ssum += __shfl_xor(ssum, msk);
                nvp  += __shfl_xor(nvp, msk);
                cfp  += __shfl_xor(cfp, msk);
            }
            if (lane == 0) {
                int n = n0 + w * 2 + ni;
                size_t idx = ((size_t)(b * 7 + v) * 2 + s) * 1024 + n;
                nv_out[idx] = nvp / ssum;
                cf_out[idx] = cfp * (1.f / 32.f) + cbs;
            }
        }
    }
}

// ================= combine (round-4 verified) ==============================
__global__ void combine_kernel(const float* __restrict__ nv, const float* __restrict__ cf,
                               float* __restrict__ novel) {
    int tid = blockIdx.x * 256 + threadIdx.x;
    if (tid >= 2 * 7 * 1024) return;
    int n = tid & 1023;
    int bv = tid >> 10;
    size_t i0 = ((size_t)bv * 2 + 0) * 1024 + n;
    size_t i1 = ((size_t)bv * 2 + 1) * 1024 + n;
    float c0 = cf[i0], c1 = cf[i1];
    float mx = fmaxf(c0, c1);
    float e0 = __expf(c0 - mx), e1 = __expf(c1 - mx);
    novel[tid] = (e0 * nv[i0] + e1 * nv[i1]) / (e0 + e1);
}

// ================= convlast: 64 -> 1 + bias + residual =====================
__global__ __launch_bounds__(256) void convlast_kernel(
    const u16* __restrict__ in,     // [14][1024][64] bf16 ch-last
    const float* __restrict__ wts,  // [64][9]
    const float* __restrict__ bias, // [1]
    const float* __restrict__ resid,// [14][1024] f32
    float* __restrict__ out)        // [14][1024] f32
{
    __shared__ float sw3[576];
    const int t = threadIdx.x;
    for (int i = t; i < 576; i += 256) sw3[i] = wts[i];
    __syncthreads();

    const int tid = blockIdx.x * 256 + t;
    const int m = tid >> 10, p = tid & 1023;
    const int y = p >> 5, x = p & 31;
    float a = bias[0] + resid[tid];
    const u16* im = in + ((size_t)m * 1024 + p) * 64;
#pragma unroll
    for (int dy = 0; dy < 3; ++dy) {
        int yy = y + dy - 1;
        if (yy < 0 || yy >= 32) continue;
#pragma unroll
        for (int dx = 0; dx < 3; ++dx) {
            int xx = x + dx - 1;
            if (xx < 0 || xx >= 32) continue;
            const u16* ip = im + (size_t)((dy - 1) * 32 + (dx - 1)) * 64;
            const int tap = dy * 3 + dx;
#pragma unroll
            for (int cg = 0; cg < 8; ++cg) {
                u16x8 raw = *(const u16x8*)(ip + cg * 8);
#pragma unroll
                for (int e = 0; e < 8; ++e)
                    a = fmaf(bf2f(raw[e]), sw3[(cg * 8 + e) * 9 + tap], a);
            }
        }
    }
    out[tid] = a;
}

// ---------------- launch ----------------
extern "C" void kernel_launch(void* const* d_in, const int* in_sizes, int n_in,
                              void* d_out, int out_size, void* d_ws, size_t ws_size,
                              hipStream_t stream) {
    const float* lf   = (const float*)d_in[0];
    const float* flow = (const float*)d_in[1];
    const float* wp   = (const float*)d_in[2];
    const float* pl   = (const float*)d_in[3];
    const float* pr   = (const float*)d_in[4];
    float* ws = (float*)d_ws;

    // feature net (4 images, 32x63, ch-last bf16 pipeline)
    conv1_kernel<63, 2016><<<dim3(8, 8, 4), 256, 0, stream>>>(
        flow, lf, wp, (const float*)d_in[5], (const float*)d_in[6],
        (u16*)(ws + X1));
    convmfma_kernel<63, 2016><<<dim3(32, 4), 256, 0, stream>>>(
        (const u16*)(ws + X1), (const float*)d_in[7], (const float*)d_in[8],
        (u16*)(ws + X2));
    convmfma_kernel<63, 2016><<<dim3(32, 4), 256, 0, stream>>>(
        (const u16*)(ws + X2), (const float*)d_in[9], (const float*)d_in[10],
        (u16*)(ws + FEATBF));

    mlp_mfma_kernel<<<512, 256, 0, stream>>>(
        lf, flow, (const u16*)(ws + FEATBF),
        (const float*)d_in[11], (const float*)d_in[12],
        (const float*)d_in[13], (const float*)d_in[14],
        (const float*)d_in[15], (const float*)d_in[16],
        (const float*)d_in[17], (const float*)d_in[18],
        ws + NVOFF, ws + CFOFF);

    combine_kernel<<<56, 256, 0, stream>>>(ws + NVOFF, ws + CFOFF, ws + NOVEL);

    // refinement net (14 images, 32x32)
    conv1_kernel<32, 1024><<<dim3(8, 4, 14), 256, 0, stream>>>(
        ws + NOVEL, pl, pr, (const float*)d_in[19], (const float*)d_in[20],
        (u16*)(ws + Y1));
    convmfma_kernel<32, 1024><<<dim3(16, 14), 256, 0, stream>>>(
        (const u16*)(ws + Y1), (const float*)d_in[21], (const float*)d_in[22],
        (u16*)(ws + Y2));
    convlast_kernel<<<56, 256, 0, stream>>>(
        (const u16*)(ws + Y2), (const float*)d_in[23], (const float*)d_in[24],
        ws + NOVEL, (float*)d_out);
}